// Round 3
// baseline (358.040 us; speedup 1.0000x reference)
//
#include <hip/hip_runtime.h>

typedef __attribute__((ext_vector_type(8))) short s16x8;   // 8 bf16 MFMA A/B frag
typedef __attribute__((ext_vector_type(4))) short s16x4;
typedef __attribute__((ext_vector_type(4))) float f32x4;   // MFMA C/D frag

#define ST 72   // LDS row stride (shorts): 144 B -> b128 frag reads are 2-way (free)
#define NB 8    // batches per block; grid = 1024 = 4 blocks/CU
#define MFMA __builtin_amdgcn_mfma_f32_16x16x32_bf16

__device__ __forceinline__ short f2bf(float f) {
    unsigned u = __builtin_bit_cast(unsigned, f);
    u += 0x7FFFu + ((u >> 16) & 1u);   // RTNE
    return (short)(u >> 16);
}
__device__ __forceinline__ s16x8 cvt8(f32x4 a, f32x4 b) {
    s16x8 r = { f2bf(a.x), f2bf(a.y), f2bf(a.z), f2bf(a.w),
                f2bf(b.x), f2bf(b.y), f2bf(b.z), f2bf(b.w) };
    return r;
}
__device__ __forceinline__ s16x4 pack4(f32x4 a) {
    s16x4 r = { f2bf(a.x), f2bf(a.y), f2bf(a.z), f2bf(a.w) };
    return r;
}

__global__ __launch_bounds__(256, 4) void sam3e_v3(
    const float* __restrict__ F, const float* __restrict__ Kw,
    const float* __restrict__ Qw, float* __restrict__ out)
{
    // A^T [d][n], KF row-major [m][e], S row-major [n][m] — all bf16
    __shared__ __align__(16) short sAT[64 * ST];
    __shared__ __align__(16) short sKF[64 * ST];
    __shared__ __align__(16) short sS [64 * ST];

    const int tid  = threadIdx.x;
    const int w    = tid >> 6;      // wave id = its 16-row n/m band
    const int lane = tid & 63;
    const int col  = lane & 15;
    const int q    = lane >> 4;

    // ---- K, Q as register A-op frags: Kf[i][h] = rows e=16i+col, k=d=32h+8q+j ----
    s16x8 Kf[4][2], Qf[4][2];
    #pragma unroll
    for (int i = 0; i < 4; ++i) {
        const float* kr = Kw + (16 * i + col) * 64 + 8 * q;
        const float* qr = Qw + (16 * i + col) * 64 + 8 * q;
        Kf[i][0] = cvt8(*(const f32x4*)kr,        *(const f32x4*)(kr + 4));
        Kf[i][1] = cvt8(*(const f32x4*)(kr + 32), *(const f32x4*)(kr + 36));
        Qf[i][0] = cvt8(*(const f32x4*)qr,        *(const f32x4*)(qr + 4));
        Qf[i][1] = cvt8(*(const f32x4*)(qr + 32), *(const f32x4*)(qr + 36));
    }

    // staging: thread owns 4x4 block: rows n=4*n4.., cols d=4*dq..
    const int n4 = tid & 15;
    const int dq = tid >> 4;
    const int nb0 = 4 * n4;
    const f32x4 z4 = {0.f, 0.f, 0.f, 0.f};

    int b = blockIdx.x * NB;
    f32x4 pf[4];
    #pragma unroll
    for (int rr = 0; rr < 4; ++rr)
        pf[rr] = (nb0 + rr < 50)
            ? *(const f32x4*)(F + (size_t)b * 3200 + (nb0 + rr) * 64 + 4 * dq) : z4;

    for (int it = 0; it < NB; ++it, ++b) {
        const float* Fb = F   + (size_t)b * 3200;
        float*       Ob = out + (size_t)b * 3200;

        __syncthreads();   // bar1: prev iter's step-3 readers of sAT/sS done

        // ---- stage sAT[d][n] via in-register 4x4 transpose -> 4 b64 writes ----
        #pragma unroll
        for (int c = 0; c < 3 + 1; ++c) {
            f32x4 t = { pf[0][c], pf[1][c], pf[2][c], pf[3][c] };
            *(s16x4*)&sAT[(4 * dq + c) * ST + nb0] = pack4(t);
        }

        // ---- A-row frags for this wave's band, direct from global (L2-hot) ----
        s16x8 a0, a1;
        {
            const int row = 16 * w + col;
            f32x4 v0 = z4, v1 = z4, v2 = z4, v3 = z4;
            if (row < 50) {
                const float* Fr = Fb + row * 64 + 8 * q;
                v0 = *(const f32x4*)Fr;        v1 = *(const f32x4*)(Fr + 4);
                v2 = *(const f32x4*)(Fr + 32); v3 = *(const f32x4*)(Fr + 36);
            }
            a0 = cvt8(v0, v1); a1 = cvt8(v2, v3);
        }

        // ---- step 1: KF^T = K·A^T  (rows e from Kf, cols m from a-frags) ----
        // store row-major sKF[m][e]: lane owns col m=16w+col, rows e=16i+4q..+3 -> b64
        #pragma unroll
        for (int i = 0; i < 4; ++i) {
            f32x4 acc = z4;
            acc = MFMA(Kf[i][0], a0, acc, 0, 0, 0);
            acc = MFMA(Kf[i][1], a1, acc, 0, 0, 0);
            *(s16x4*)&sKF[(16 * w + col) * ST + 16 * i + 4 * q] = pack4(acc);
        }
        __syncthreads();   // bar2: sKF (and sAT) visible

        // ---- prefetch next batch's staging block (in flight across step2+3) ----
        if (it + 1 < NB) {
            #pragma unroll
            for (int rr = 0; rr < 4; ++rr)
                pf[rr] = (nb0 + rr < 50)
                    ? *(const f32x4*)(Fb + 3200 + (nb0 + rr) * 64 + 4 * dq) : z4;
        }

        // ---- step 2: S^T = KF·A^T (rows m from sKF frags, cols n from a-frags) ----
        // store row-major sS[n][m]: lane owns col n=16w+col, rows m=16i+4q..+3 -> b64
        #pragma unroll
        for (int i = 0; i < 4; ++i) {
            s16x8 kf0 = *(const s16x8*)&sKF[(16 * i + col) * ST + 8 * q];
            s16x8 kf1 = *(const s16x8*)&sKF[(16 * i + col) * ST + 32 + 8 * q];
            f32x4 acc = z4;
            acc = MFMA(kf0, a0, acc, 0, 0, 0);
            acc = MFMA(kf1, a1, acc, 0, 0, 0);
            *(s16x4*)&sS[(16 * w + col) * ST + 16 * i + 4 * q] = pack4(acc);
        }
        __syncthreads();   // bar3: sS visible

        // ---- step 3: T = S·A (A_op = S rows, B_op = A^T), Q = A·Q^T; epilogue ----
        s16x8 s0 = *(const s16x8*)&sS[(16 * w + col) * ST + 8 * q];
        s16x8 s1 = *(const s16x8*)&sS[(16 * w + col) * ST + 32 + 8 * q];
        #pragma unroll
        for (int nt = 0; nt < 4; ++nt) {
            s16x8 at0 = *(const s16x8*)&sAT[(16 * nt + col) * ST + 8 * q];
            s16x8 at1 = *(const s16x8*)&sAT[(16 * nt + col) * ST + 32 + 8 * q];
            f32x4 t  = z4, qa = z4;
            t  = MFMA(s0, at0, t, 0, 0, 0);
            t  = MFMA(s1, at1, t, 0, 0, 0);
            qa = MFMA(a0, Qf[nt][0], qa, 0, 0, 0);
            qa = MFMA(a1, Qf[nt][1], qa, 0, 0, 0);
            #pragma unroll
            for (int r = 0; r < 4; ++r) {
                const int n = 16 * w + 4 * q + r;
                if (n < 50) {
                    const int idx = n * 64 + 16 * nt + col;
                    Ob[idx] = Fb[idx] * t[r] + qa[r];
                }
            }
        }
    }
}

extern "C" void kernel_launch(void* const* d_in, const int* in_sizes, int n_in,
                              void* d_out, int out_size, void* d_ws, size_t ws_size,
                              hipStream_t stream) {
    const float* F  = (const float*)d_in[0];   // [8192,50,64]
    const float* Kw = (const float*)d_in[1];   // [64,64]
    const float* Qw = (const float*)d_in[2];   // [64,64]
    float* out = (float*)d_out;
    sam3e_v3<<<8192 / NB, 256, 0, stream>>>(F, Kw, Qw, out);
}